// Round 2
// 892.326 us; speedup vs baseline: 1.0920x; 1.0920x over previous
//
#include <hip/hip_runtime.h>
#include <stdint.h>

typedef _Float16 half8 __attribute__((ext_vector_type(8)));
typedef float f32x4 __attribute__((ext_vector_type(4)));

constexpr int E_EDGES = 800000;
constexpr int HD = 128;          // hidden dim
constexpr int RS = 136;          // LDS h row stride in halves: 272 B = 16B-aligned, odd dword count

// Pack W1 [256x128] and W2 [128x128] (row-major f32) into f16 MFMA B-fragment layout:
// frag element t = ((ks*8 + nt)*64 + lane)*8 + j  holds  W[k = ks*32 + (lane>>4)*8 + j][n = nt*16 + (lane&15)]
__global__ __launch_bounds__(256) void pack_weights(
    const float* __restrict__ W1, const float* __restrict__ W2,
    _Float16* __restrict__ W1p, _Float16* __restrict__ W2p)
{
    int t = blockIdx.x * 256 + threadIdx.x;
    if (t < 32768) {                     // W1: 8 ks * 8 nt * 64 * 8
        int j = t & 7, lane = (t >> 3) & 63, nt = (t >> 9) & 7, ks = t >> 12;
        int k = ks * 32 + (lane >> 4) * 8 + j;
        int n = nt * 16 + (lane & 15);
        W1p[t] = (_Float16)W1[k * HD + n];
    } else if (t < 49152) {              // W2: 4 ks * 8 nt * 64 * 8
        int q = t - 32768;
        int j = q & 7, lane = (q >> 3) & 63, nt = (q >> 9) & 7, ks = q >> 12;
        int k = ks * 32 + (lane >> 4) * 8 + j;
        int n = nt * 16 + (lane & 15);
        W2p[q] = (_Float16)W2[k * HD + n];
    }
}

__device__ __forceinline__ half8 cvt8(float4 a, float4 b)
{
    half8 h;
    h[0] = (_Float16)a.x; h[1] = (_Float16)a.y; h[2] = (_Float16)a.z; h[3] = (_Float16)a.w;
    h[4] = (_Float16)b.x; h[5] = (_Float16)b.y; h[6] = (_Float16)b.z; h[7] = (_Float16)b.w;
    return h;
}

// Block = 256 threads = 4 waves; each wave owns 32 edges (2 M-tiles of 16) x all 128 output cols.
// Restructured for memory-level parallelism: all X gather loads issued in a batch (16 dwordx4
// in flight per m-tile), X held resident as f16 fragments, GEMM1 split into two N-halves so
// acc pressure leaves room for B-fragment prefetch. launch_bounds(256,4) caps VGPR at 128
// (LDS caps occupancy at 4 blocks/CU = 16 waves/CU anyway).
__global__ __launch_bounds__(256, 4) void edge_update(
    const float* __restrict__ node_inv,
    const float* __restrict__ edge_feat,
    const int* __restrict__ esrc,        // harness delivers int64 reference indices as int32
    const int* __restrict__ edst,
    const float* __restrict__ b1v,
    const float* __restrict__ b2v,
    const float* __restrict__ gammav,
    const float* __restrict__ betav,
    const _Float16* __restrict__ W1p,
    const _Float16* __restrict__ W2p,
    float* __restrict__ out)
{
    __shared__ __align__(16) _Float16 hl[4 * 32 * RS];

    const int tid  = threadIdx.x;
    const int lane = tid & 63;
    const int w    = tid >> 6;
    const int quad = lane >> 4;
    const int c    = lane & 15;
    const int rb   = blockIdx.x * 128 + w * 32;   // wave's first edge row
    const int rA0  = rb + c;                      // A-operand row, m-tile 0  (A: m = lane&15)
    const int rA1  = rb + 16 + c;                 // A-operand row, m-tile 1

    const int s0 = esrc[rA0], d0 = edst[rA0];
    const int s1 = esrc[rA1], d1 = edst[rA1];

    // ---------------- Phase A: batched X loads -> resident f16 A-fragments ----------------
    // X row layout: cols [0:64) = node_inv[src], [64:128) = node_inv[dst], [128:256) = edge_feat.
    // Per lane: k = ks*32 + quad*8 + j, j = 0..7 -> two float4 per ks-step.
    const float* ps0 = node_inv + (long long)s0 * 64 + quad * 8;
    const float* pd0 = node_inv + (long long)d0 * 64 + quad * 8;
    const float* pe0 = edge_feat + (long long)rA0 * HD + quad * 8;
    const float* ps1 = node_inv + (long long)s1 * 64 + quad * 8;
    const float* pd1 = node_inv + (long long)d1 * 64 + quad * 8;
    const float* pe1 = edge_feat + (long long)rA1 * HD + quad * 8;

    half8 xa0[8], xa1[8];
    {
        float4 xf[16];                    // m-tile 0: all 16 loads issued before any use
#pragma unroll
        for (int ks = 0; ks < 8; ++ks) {
            const float* pa = ks < 2 ? ps0 + ks * 32
                            : ks < 4 ? pd0 + (ks - 2) * 32
                                     : pe0 + (ks - 4) * 32;
            xf[ks * 2]     = ((const float4*)pa)[0];
            xf[ks * 2 + 1] = ((const float4*)pa)[1];
        }
#pragma unroll
        for (int ks = 0; ks < 8; ++ks)
            xa0[ks] = cvt8(xf[ks * 2], xf[ks * 2 + 1]);
    }
    {
        float4 xf[16];                    // m-tile 1
#pragma unroll
        for (int ks = 0; ks < 8; ++ks) {
            const float* pa = ks < 2 ? ps1 + ks * 32
                            : ks < 4 ? pd1 + (ks - 2) * 32
                                     : pe1 + (ks - 4) * 32;
            xf[ks * 2]     = ((const float4*)pa)[0];
            xf[ks * 2 + 1] = ((const float4*)pa)[1];
        }
#pragma unroll
        for (int ks = 0; ks < 8; ++ks)
            xa1[ks] = cvt8(xf[ks * 2], xf[ks * 2 + 1]);
    }

    float bini[8];
#pragma unroll
    for (int nt = 0; nt < 8; ++nt) bini[nt] = b1v[nt * 16 + c];

    _Float16* hw = hl + w * 32 * RS;

    // ---------------- GEMM1: X[32x256] @ W1 in two N-halves (acc = 32 VGPRs each) ----------------
#pragma unroll
    for (int nh = 0; nh < 2; ++nh) {
        f32x4 a0c[4], a1c[4];
#pragma unroll
        for (int nt = 0; nt < 4; ++nt) {
            float bv = bini[nh * 4 + nt];          // C/D: col = (nh*4+nt)*16 + (lane&15)
            a0c[nt] = (f32x4){bv, bv, bv, bv};
            a1c[nt] = a0c[nt];
        }
#pragma unroll
        for (int ks = 0; ks < 8; ++ks) {
#pragma unroll
            for (int nt = 0; nt < 4; ++nt) {
                half8 bfr = *(const half8*)(W1p + (((ks * 8 + nh * 4 + nt) * 64 + lane) << 3));
                a0c[nt] = __builtin_amdgcn_mfma_f32_16x16x32_f16(xa0[ks], bfr, a0c[nt], 0, 0, 0);
                a1c[nt] = __builtin_amdgcn_mfma_f32_16x16x32_f16(xa1[ks], bfr, a1c[nt], 0, 0, 0);
            }
        }
        // ReLU + C-layout -> row-major h in LDS (f16); row = quad*4+r, col = (nh*4+nt)*16+c
#pragma unroll
        for (int nt = 0; nt < 4; ++nt)
#pragma unroll
            for (int r = 0; r < 4; ++r) {
                float v0 = a0c[nt][r]; v0 = v0 > 0.f ? v0 : 0.f;
                hw[(quad * 4 + r) * RS + nh * 64 + nt * 16 + c] = (_Float16)v0;
                float v1 = a1c[nt][r]; v1 = v1 > 0.f ? v1 : 0.f;
                hw[(16 + quad * 4 + r) * RS + nh * 64 + nt * 16 + c] = (_Float16)v1;
            }
    }

    // h tile is wave-private, but use the plain barrier: it is executed once per wave
    // (all vmem already consumed, so the vmcnt(0) drain is ~free) and avoids the
    // inline-asm-wait + scheduler-hoisting hazard (guide rule #18).
    __syncthreads();

    // preload GEMM2 bias + LN params so their latency hides under MFMA
    float b2i[8], gv[8], btv[8];
#pragma unroll
    for (int nt = 0; nt < 8; ++nt) {
        b2i[nt] = b2v[nt * 16 + c];
        gv[nt]  = gammav[nt * 16 + c];
        btv[nt] = betav[nt * 16 + c];
    }

    // ---------------- GEMM2: h[32x128] @ W2, K = 4 steps of 32, full N ----------------
    f32x4 acc[2][8];
#pragma unroll
    for (int nt = 0; nt < 8; ++nt) {
        acc[0][nt] = (f32x4){b2i[nt], b2i[nt], b2i[nt], b2i[nt]};
        acc[1][nt] = acc[0][nt];
    }
#pragma unroll
    for (int ks = 0; ks < 4; ++ks) {
        half8 a0 = *(const half8*)(hw + c * RS + ks * 32 + quad * 8);
        half8 a1 = *(const half8*)(hw + (16 + c) * RS + ks * 32 + quad * 8);
#pragma unroll
        for (int nt = 0; nt < 8; ++nt) {
            half8 bfr = *(const half8*)(W2p + (((ks * 8 + nt) * 64 + lane) << 3));
            acc[0][nt] = __builtin_amdgcn_mfma_f32_16x16x32_f16(a0, bfr, acc[0][nt], 0, 0, 0);
            acc[1][nt] = __builtin_amdgcn_mfma_f32_16x16x32_f16(a1, bfr, acc[1][nt], 0, 0, 0);
        }
    }

    // ---------------- LayerNorm (quad owns whole rows) + residual ----------------
#pragma unroll
    for (int m = 0; m < 2; ++m) {
        const int rowg = rb + m * 16 + quad * 4;

        // prefetch residual reads for this m-tile before the shfl-reduce chain
        float res[8][4];
#pragma unroll
        for (int nt = 0; nt < 8; ++nt)
#pragma unroll
            for (int r = 0; r < 4; ++r)
                res[nt][r] = edge_feat[(long long)(rowg + r) * HD + nt * 16 + c];

        float sum[4] = {0, 0, 0, 0}, sq[4] = {0, 0, 0, 0};
#pragma unroll
        for (int nt = 0; nt < 8; ++nt)
#pragma unroll
            for (int r = 0; r < 4; ++r) {
                float v = acc[m][nt][r];
                sum[r] += v;
                sq[r]  += v * v;
            }
        // reduce across the 16 lanes of the quad (rows are quad-local)
#pragma unroll
        for (int mask = 1; mask < 16; mask <<= 1)
#pragma unroll
            for (int r = 0; r < 4; ++r) {
                sum[r] += __shfl_xor(sum[r], mask);
                sq[r]  += __shfl_xor(sq[r], mask);
            }
        float mu[4], rstd[4];
#pragma unroll
        for (int r = 0; r < 4; ++r) {
            mu[r] = sum[r] * (1.0f / 128.0f);
            float var = sq[r] * (1.0f / 128.0f) - mu[r] * mu[r];
            rstd[r] = rsqrtf(var + 1e-5f);
        }
#pragma unroll
        for (int nt = 0; nt < 8; ++nt)
#pragma unroll
            for (int r = 0; r < 4; ++r) {
                long long idx = (long long)(rowg + r) * HD + nt * 16 + c;
                float v = res[nt][r] + (acc[m][nt][r] - mu[r]) * rstd[r] * gv[nt] + btv[nt];
                __builtin_nontemporal_store(v, &out[idx]);
            }
    }
}

extern "C" void kernel_launch(void* const* d_in, const int* in_sizes, int n_in,
                              void* d_out, int out_size, void* d_ws, size_t ws_size,
                              hipStream_t stream)
{
    const float* node_inv  = (const float*)d_in[0];
    const float* edge_feat = (const float*)d_in[1];
    const int*   esrc      = (const int*)d_in[2];
    const int*   edst      = (const int*)d_in[3];
    const float* W1        = (const float*)d_in[4];
    const float* b1        = (const float*)d_in[5];
    const float* W2        = (const float*)d_in[6];
    const float* b2        = (const float*)d_in[7];
    const float* gamma     = (const float*)d_in[8];
    const float* beta      = (const float*)d_in[9];

    _Float16* W1p = (_Float16*)d_ws;          // 32768 halves = 64 KB
    _Float16* W2p = W1p + 32768;              // 16384 halves = 32 KB

    pack_weights<<<192, 256, 0, stream>>>(W1, W2, W1p, W2p);
    edge_update<<<E_EDGES / 128, 256, 0, stream>>>(node_inv, edge_feat, esrc, edst,
                                                   b1, b2, gamma, beta, W1p, W2p,
                                                   (float*)d_out);
}

// Round 3
// 879.473 us; speedup vs baseline: 1.1080x; 1.0146x over previous
//
#include <hip/hip_runtime.h>
#include <stdint.h>

typedef _Float16 half8 __attribute__((ext_vector_type(8)));
typedef float f32x4 __attribute__((ext_vector_type(4)));

constexpr int E_EDGES = 800000;
constexpr int N_NODES = 50000;
constexpr int HD = 128;          // hidden dim
constexpr int RS = 136;          // LDS h row stride in halves: 272 B (16B-aligned, 2-way-free banks)

// Pack W1 [256x128] and W2 [128x128] (row-major f32) into f16 MFMA B-fragment layout:
// frag element t = ((ks*8 + nt)*64 + lane)*8 + j  holds  W[k = ks*32 + (lane>>4)*8 + j][n = nt*16 + (lane&15)]
__global__ __launch_bounds__(256) void pack_weights(
    const float* __restrict__ W1, const float* __restrict__ W2,
    _Float16* __restrict__ W1p, _Float16* __restrict__ W2p)
{
    int t = blockIdx.x * 256 + threadIdx.x;
    if (t < 32768) {                     // W1: 8 ks * 8 nt * 64 * 8
        int j = t & 7, lane = (t >> 3) & 63, nt = (t >> 9) & 7, ks = t >> 12;
        int k = ks * 32 + (lane >> 4) * 8 + j;
        int n = nt * 16 + (lane & 15);
        W1p[t] = (_Float16)W1[k * HD + n];
    } else if (t < 49152) {              // W2: 4 ks * 8 nt * 64 * 8
        int q = t - 32768;
        int j = q & 7, lane = (q >> 3) & 63, nt = (q >> 9) & 7, ks = q >> 12;
        int k = ks * 32 + (lane >> 4) * 8 + j;
        int n = nt * 16 + (lane & 15);
        W2p[q] = (_Float16)W2[k * HD + n];
    }
}

// node_inv f32 [50000x64] -> f16 table, same row-major layout. Rounding identical to the
// in-kernel (_Float16) cvt the f32 path performs, so numerics are unchanged.
__global__ __launch_bounds__(256) void pack_nodes(
    const float* __restrict__ ni, _Float16* __restrict__ nh)
{
    int t = blockIdx.x * 256 + threadIdx.x;      // 800000 threads x 4 elements
    if (t < N_NODES * 16) {
        float4 v = ((const float4*)ni)[t];
        _Float16* p = nh + t * 4;
        p[0] = (_Float16)v.x; p[1] = (_Float16)v.y; p[2] = (_Float16)v.z; p[3] = (_Float16)v.w;
    }
}

__device__ __forceinline__ half8 cvt8(float4 a, float4 b)
{
    half8 h;
    h[0] = (_Float16)a.x; h[1] = (_Float16)a.y; h[2] = (_Float16)a.z; h[3] = (_Float16)a.w;
    h[4] = (_Float16)b.x; h[5] = (_Float16)b.y; h[6] = (_Float16)b.z; h[7] = (_Float16)b.w;
    return h;
}

// Block = 256 threads = 4 waves; each wave owns 32 edges (2 M-tiles of 16) x all 128 output cols.
// F16TAB path: node gathers come from the pre-packed f16 table -> one dwordx4 per row-slice,
// whole X batch = 12 loads / 48 dest VGPRs, fenced with sched_barrier so all stay in flight.
template<bool F16TAB>
__global__ __launch_bounds__(256, 4) void edge_update(
    const float* __restrict__ node_inv,
    const _Float16* __restrict__ node_h,
    const float* __restrict__ edge_feat,
    const int* __restrict__ esrc,        // harness delivers int64 reference indices as int32
    const int* __restrict__ edst,
    const float* __restrict__ b1v,
    const float* __restrict__ b2v,
    const float* __restrict__ gammav,
    const float* __restrict__ betav,
    const _Float16* __restrict__ W1p,
    const _Float16* __restrict__ W2p,
    float* __restrict__ out)
{
    __shared__ __align__(16) _Float16 hl[4 * 32 * RS];

    const int tid  = threadIdx.x;
    const int lane = tid & 63;
    const int w    = tid >> 6;
    const int quad = lane >> 4;
    const int c    = lane & 15;
    const int rb   = blockIdx.x * 128 + w * 32;   // wave's first edge row
    const int rA0  = rb + c;                      // A-operand row, m-tile 0  (A: m = lane&15)
    const int rA1  = rb + 16 + c;                 // A-operand row, m-tile 1

    const int s0 = esrc[rA0], d0 = edst[rA0];
    const int s1 = esrc[rA1], d1 = edst[rA1];

    // ---------------- Phase A: batched X loads -> resident f16 A-fragments ----------------
    // X row layout: cols [0:64) = node_inv[src], [64:128) = node_inv[dst], [128:256) = edge_feat.
    // A-frag xa[ks]: k = ks*32 + quad*8 + j.
    half8 xa0[8], xa1[8];

    if constexpr (F16TAB) {
        const _Float16* ns0 = node_h + (long long)s0 * 64 + quad * 8;
        const _Float16* nd0 = node_h + (long long)d0 * 64 + quad * 8;
        const _Float16* ns1 = node_h + (long long)s1 * 64 + quad * 8;
        const _Float16* nd1 = node_h + (long long)d1 * 64 + quad * 8;
        const float*    pe0 = edge_feat + (long long)rA0 * HD + quad * 8;
        const float*    pe1 = edge_feat + (long long)rA1 * HD + quad * 8;

        // issue ALL 12 loads (4 f16 gather pairs + 8 ef float4) before any cvt
        half8 s0a = *(const half8*)(ns0);
        half8 s0b = *(const half8*)(ns0 + 32);
        half8 d0a = *(const half8*)(nd0);
        half8 d0b = *(const half8*)(nd0 + 32);
        half8 s1a = *(const half8*)(ns1);
        half8 s1b = *(const half8*)(ns1 + 32);
        half8 d1a = *(const half8*)(nd1);
        half8 d1b = *(const half8*)(nd1 + 32);
        float4 e0[8], e1[8];
#pragma unroll
        for (int q = 0; q < 8; ++q) e0[q] = ((const float4*)pe0)[(q >> 1) * 8 + (q & 1)];
#pragma unroll
        for (int q = 0; q < 8; ++q) e1[q] = ((const float4*)pe1)[(q >> 1) * 8 + (q & 1)];
        __builtin_amdgcn_sched_barrier(0);   // keep every load issued before the cvt chain

        xa0[0] = s0a; xa0[1] = s0b; xa0[2] = d0a; xa0[3] = d0b;
        xa1[0] = s1a; xa1[1] = s1b; xa1[2] = d1a; xa1[3] = d1b;
#pragma unroll
        for (int q = 0; q < 4; ++q) {
            xa0[4 + q] = cvt8(e0[q * 2], e0[q * 2 + 1]);
            xa1[4 + q] = cvt8(e1[q * 2], e1[q * 2 + 1]);
        }
    } else {
        const float* ps0 = node_inv + (long long)s0 * 64 + quad * 8;
        const float* pd0 = node_inv + (long long)d0 * 64 + quad * 8;
        const float* pe0 = edge_feat + (long long)rA0 * HD + quad * 8;
        const float* ps1 = node_inv + (long long)s1 * 64 + quad * 8;
        const float* pd1 = node_inv + (long long)d1 * 64 + quad * 8;
        const float* pe1 = edge_feat + (long long)rA1 * HD + quad * 8;
        {
            float4 xf[16];
#pragma unroll
            for (int ks = 0; ks < 8; ++ks) {
                const float* pa = ks < 2 ? ps0 + ks * 32
                                : ks < 4 ? pd0 + (ks - 2) * 32
                                         : pe0 + (ks - 4) * 32;
                xf[ks * 2]     = ((const float4*)pa)[0];
                xf[ks * 2 + 1] = ((const float4*)pa)[1];
            }
#pragma unroll
            for (int ks = 0; ks < 8; ++ks)
                xa0[ks] = cvt8(xf[ks * 2], xf[ks * 2 + 1]);
        }
        {
            float4 xf[16];
#pragma unroll
            for (int ks = 0; ks < 8; ++ks) {
                const float* pa = ks < 2 ? ps1 + ks * 32
                                : ks < 4 ? pd1 + (ks - 2) * 32
                                         : pe1 + (ks - 4) * 32;
                xf[ks * 2]     = ((const float4*)pa)[0];
                xf[ks * 2 + 1] = ((const float4*)pa)[1];
            }
#pragma unroll
            for (int ks = 0; ks < 8; ++ks)
                xa1[ks] = cvt8(xf[ks * 2], xf[ks * 2 + 1]);
        }
    }

    float bini[8];
#pragma unroll
    for (int nt = 0; nt < 8; ++nt) bini[nt] = b1v[nt * 16 + c];

    _Float16* hw = hl + w * 32 * RS;

    // ---------------- GEMM1: X[32x256] @ W1 in two N-halves (acc = 32 VGPRs each) ----------------
#pragma unroll
    for (int nh = 0; nh < 2; ++nh) {
        f32x4 a0c[4], a1c[4];
#pragma unroll
        for (int nt = 0; nt < 4; ++nt) {
            float bv = bini[nh * 4 + nt];          // C/D: col = (nh*4+nt)*16 + (lane&15)
            a0c[nt] = (f32x4){bv, bv, bv, bv};
            a1c[nt] = a0c[nt];
        }
#pragma unroll
        for (int ks = 0; ks < 8; ++ks) {
#pragma unroll
            for (int nt = 0; nt < 4; ++nt) {
                half8 bfr = *(const half8*)(W1p + (((ks * 8 + nh * 4 + nt) * 64 + lane) << 3));
                a0c[nt] = __builtin_amdgcn_mfma_f32_16x16x32_f16(xa0[ks], bfr, a0c[nt], 0, 0, 0);
                a1c[nt] = __builtin_amdgcn_mfma_f32_16x16x32_f16(xa1[ks], bfr, a1c[nt], 0, 0, 0);
            }
        }
        // ReLU + C-layout -> row-major h in LDS (f16); row = quad*4+r, col = (nh*4+nt)*16+c
#pragma unroll
        for (int nt = 0; nt < 4; ++nt)
#pragma unroll
            for (int r = 0; r < 4; ++r) {
                float v0 = a0c[nt][r]; v0 = v0 > 0.f ? v0 : 0.f;
                hw[(quad * 4 + r) * RS + nh * 64 + nt * 16 + c] = (_Float16)v0;
                float v1 = a1c[nt][r]; v1 = v1 > 0.f ? v1 : 0.f;
                hw[(16 + quad * 4 + r) * RS + nh * 64 + nt * 16 + c] = (_Float16)v1;
            }
    }

    // h tile is wave-private, but the plain barrier is executed once and all vmem is already
    // consumed here, so its drain is ~free; avoids the inline-asm-wait hazard (rule #18).
    __syncthreads();

    // preload GEMM2 bias + LN params so their latency hides under MFMA
    float b2i[8], gv[8], btv[8];
#pragma unroll
    for (int nt = 0; nt < 8; ++nt) {
        b2i[nt] = b2v[nt * 16 + c];
        gv[nt]  = gammav[nt * 16 + c];
        btv[nt] = betav[nt * 16 + c];
    }

    // ---------------- GEMM2: h[32x128] @ W2, K = 4 steps of 32, full N ----------------
    f32x4 acc[2][8];
#pragma unroll
    for (int nt = 0; nt < 8; ++nt) {
        acc[0][nt] = (f32x4){b2i[nt], b2i[nt], b2i[nt], b2i[nt]};
        acc[1][nt] = acc[0][nt];
    }
#pragma unroll
    for (int ks = 0; ks < 4; ++ks) {
        half8 a0 = *(const half8*)(hw + c * RS + ks * 32 + quad * 8);
        half8 a1 = *(const half8*)(hw + (16 + c) * RS + ks * 32 + quad * 8);
#pragma unroll
        for (int nt = 0; nt < 8; ++nt) {
            half8 bfr = *(const half8*)(W2p + (((ks * 8 + nt) * 64 + lane) << 3));
            acc[0][nt] = __builtin_amdgcn_mfma_f32_16x16x32_f16(a0, bfr, acc[0][nt], 0, 0, 0);
            acc[1][nt] = __builtin_amdgcn_mfma_f32_16x16x32_f16(a1, bfr, acc[1][nt], 0, 0, 0);
        }
    }

    // ---------------- LayerNorm (quad owns whole rows) + residual ----------------
#pragma unroll
    for (int m = 0; m < 2; ++m) {
        const int rowg = rb + m * 16 + quad * 4;

        // prefetch residual reads for this m-tile before the shfl-reduce chain
        float res[8][4];
#pragma unroll
        for (int nt = 0; nt < 8; ++nt)
#pragma unroll
            for (int r = 0; r < 4; ++r)
                res[nt][r] = edge_feat[(long long)(rowg + r) * HD + nt * 16 + c];

        float sum[4] = {0, 0, 0, 0}, sq[4] = {0, 0, 0, 0};
#pragma unroll
        for (int nt = 0; nt < 8; ++nt)
#pragma unroll
            for (int r = 0; r < 4; ++r) {
                float v = acc[m][nt][r];
                sum[r] += v;
                sq[r]  += v * v;
            }
        // reduce across the 16 lanes of the quad (rows are quad-local)
#pragma unroll
        for (int mask = 1; mask < 16; mask <<= 1)
#pragma unroll
            for (int r = 0; r < 4; ++r) {
                sum[r] += __shfl_xor(sum[r], mask);
                sq[r]  += __shfl_xor(sq[r], mask);
            }
        float mu[4], rstd[4];
#pragma unroll
        for (int r = 0; r < 4; ++r) {
            mu[r] = sum[r] * (1.0f / 128.0f);
            float var = sq[r] * (1.0f / 128.0f) - mu[r] * mu[r];
            rstd[r] = rsqrtf(var + 1e-5f);
        }
        // plain cached stores: L2 merges the 64B chunks into full lines
        // (nontemporal stores cost +135MB of partial-line RMW traffic in R2)
#pragma unroll
        for (int nt = 0; nt < 8; ++nt)
#pragma unroll
            for (int r = 0; r < 4; ++r) {
                long long idx = (long long)(rowg + r) * HD + nt * 16 + c;
                out[idx] = res[nt][r] + (acc[m][nt][r] - mu[r]) * rstd[r] * gv[nt] + btv[nt];
            }
    }
}

extern "C" void kernel_launch(void* const* d_in, const int* in_sizes, int n_in,
                              void* d_out, int out_size, void* d_ws, size_t ws_size,
                              hipStream_t stream)
{
    const float* node_inv  = (const float*)d_in[0];
    const float* edge_feat = (const float*)d_in[1];
    const int*   esrc      = (const int*)d_in[2];
    const int*   edst      = (const int*)d_in[3];
    const float* W1        = (const float*)d_in[4];
    const float* b1        = (const float*)d_in[5];
    const float* W2        = (const float*)d_in[6];
    const float* b2        = (const float*)d_in[7];
    const float* gamma     = (const float*)d_in[8];
    const float* beta      = (const float*)d_in[9];

    _Float16* W1p    = (_Float16*)d_ws;       // 32768 halves = 64 KB
    _Float16* W2p    = W1p + 32768;           // 16384 halves = 32 KB
    _Float16* node_h = W2p + 16384;           // 3.2M halves = 6.4 MB (byte offset 98304, 16B-aligned)

    const size_t need = 98304 + (size_t)N_NODES * 64 * 2;
    const bool f16tab = ws_size >= need;

    pack_weights<<<192, 256, 0, stream>>>(W1, W2, W1p, W2p);
    if (f16tab) {
        pack_nodes<<<(N_NODES * 16 + 255) / 256, 256, 0, stream>>>(node_inv, node_h);
        edge_update<true><<<E_EDGES / 128, 256, 0, stream>>>(node_inv, node_h, edge_feat,
                                                             esrc, edst, b1, b2, gamma, beta,
                                                             W1p, W2p, (float*)d_out);
    } else {
        edge_update<false><<<E_EDGES / 128, 256, 0, stream>>>(node_inv, node_h, edge_feat,
                                                              esrc, edst, b1, b2, gamma, beta,
                                                              W1p, W2p, (float*)d_out);
    }
}